// Round 14
// baseline (187.480 us; speedup 1.0000x reference)
//
#include <hip/hip_runtime.h>
#include <hip/hip_cooperative_groups.h>
#include <stdint.h>

namespace cg = cooperative_groups;

typedef unsigned long long u64;
typedef unsigned int u32;

#define BN 2
#define DD 32
#define HH 192
#define WW 192
#define NV (DD*HH*WW)   /* 1179648 */
#define KK 8
#define NSL 288         /* tiles per batch, 4096 vox each */
#define VPB 4096
#define NB 256          /* buckets in window */
#define BOFF 1808       /* 0x38800000>>19 : window floor e = 2^-14 */
#define L2E 1.44269504f
#define SSLOT 11
#define NBLK 288        /* grid blocks (mega + front) */
#define SMU64 2112      /* shared union size in u64 */

__device__ __forceinline__ u64 fx(float v){ return (u64)(long long)llrintf(v*4294967296.0f); }
__device__ __forceinline__ float unfx(u64 v){ return (float)((double)(long long)v*(1.0/4294967296.0)); }
__device__ __forceinline__ float rcp_f(float x){ return __builtin_amdgcn_rcpf(x); }
__device__ __forceinline__ float exp2_f(float x){ return __builtin_amdgcn_exp2f(x); }
__device__ __forceinline__ float tanh_f(float x){ return 1.f - 2.f*rcp_f(1.f + exp2_f(x*(2.f*L2E))); }
__device__ __forceinline__ float sigm_f(float x){ return rcp_f(1.f + exp2_f(-x*L2E)); }
__device__ __forceinline__ float rfl(float x){ return __uint_as_float(__builtin_amdgcn_readfirstlane((int)__float_as_uint(x))); }

// unpack cell (b,k) from 4 shards:
// 0 cnt<<32|cm, 1..3 Six/Siy/Siz, 4..6 Ssig*4096 (signed), 7 Ss2*2048, 8..10 cm fx32
struct Cell { float cnt, cmc, mx, my, mz, g0, g1, g2, h, cmx, cmy, cmz; };
__device__ __forceinline__ Cell load_cell(const u64* __restrict__ ssh, int bb, int kq){
    u64 st[SSLOT];
    #pragma unroll
    for (int s = 0; s < SSLOT; s++){
        u64 a = 0ull;
        #pragma unroll
        for (int sh = 0; sh < 4; sh++)
            a += ssh[((size_t)(sh*BN + bb)*KK + kq)*SSLOT + s];
        st[s] = a;
    }
    Cell c;
    c.cnt = (float)(long long)(st[0] >> 32);
    c.cmc = (float)(u32)st[0];
    c.mx = (float)(long long)st[1] * (1.f/(WW-1));
    c.my = (float)(long long)st[2] * (1.f/(HH-1));
    c.mz = (float)(long long)st[3] * (1.f/(DD-1));
    c.g0 = (float)((double)(long long)st[4] * (1.0/4096.0));
    c.g1 = (float)((double)(long long)st[5] * (1.0/4096.0));
    c.g2 = (float)((double)(long long)st[6] * (1.0/4096.0));
    c.h  = (float)((double)(long long)st[7] * (1.0/2048.0));
    c.cmx = unfx(st[8]); c.cmy = unfx(st[9]); c.cmz = unfx(st[10]);
    return c;
}

// ---------------- phase: front (zero + detect chunk into fpart[bid]) ----------------
__device__ __forceinline__ void do_front(int bid, int t, const u32* __restrict__ w,
        u32* __restrict__ fpart, u64* __restrict__ zero_base, int nzero_u64,
        u32* __restrict__ counter, u32* __restrict__ sfl){
    if (bid == 0){
        for (int i = t; i < nzero_u64; i += 512) zero_base[i] = 0ull;
        if (t == 0) *counter = 0u;
    }
    if (t == 0) *sfl = 0u;
    __syncthreads();
    const int chunk = (BN*NV/4)/NBLK;   /* 2048 */
    u32 f = 0;
    for (int i = bid*chunk + t; i < (bid+1)*chunk; i += 512){
        u32 x = w[i];
        if (x == 0x3F800000u) f |= 1u;
        else if (x > 1u) f |= 2u;
        else if (x == 1u){ f |= 8u; if (i & 1) f |= 4u; }
    }
    if (f) atomicOr(sfl, f);
    __syncthreads();
    if (t == 0) fpart[bid] = *sfl;
}

// ---------------- phase: mode decode from fpart ----------------
__device__ __forceinline__ int decode_mode(int t, const u32* __restrict__ fpart, u32* __restrict__ sfl){
    if (t == 0) *sfl = 0u;
    __syncthreads();
    u32 fo = 0;
    for (int i = t; i < NBLK; i += 512) fo |= fpart[i];
    if (fo) atomicOr(sfl, fo);
    __syncthreads();
    u32 fl = *sfl;
    __syncthreads();
    return (fl & 1u) ? 2 : ((fl & 2u) ? 1 : ((fl & 4u) ? 0 : ((fl & 8u) ? 3 : 0)));
}

// ---------------- phase: stats tile (R13 body) ----------------
__device__ __forceinline__ void do_stats_tile(int sx, int b, int mode, int t,
        const float* __restrict__ pred, const int* __restrict__ inst,
        const void* __restrict__ cim, u64* __restrict__ ssh, u64* __restrict__ sm8){
    u64 (*bins)[4][25] = (u64(*)[4][25])sm8;            /* 800 u64 */
    u64 (*cmb)[KK][4]  = (u64(*)[KK][4])(sm8 + 800);    /* 256 u64 */
    for (int i = t; i < 800 + 256; i += 512) sm8[i] = 0ull;
    __syncthreads();
    const float* pb = pred + (size_t)b*7*NV;
    const int* ib = inst + (size_t)b*NV;
    int wv = t >> 6, lp = t & 3;
    int g = sx*VPB + t*8;

    const float4* q0p = (const float4*)&pb[3*(size_t)NV + g];
    const float4* q1p = (const float4*)&pb[4*(size_t)NV + g];
    const float4* q2p = (const float4*)&pb[5*(size_t)NV + g];
    float4 sa0 = q0p[0], sb0 = q0p[1];
    float4 sa1 = q1p[0], sb1 = q1p[1];
    float4 sa2 = q2p[0], sb2 = q2p[1];
    const int4* qi = (const int4*)&ib[g];
    int4 i0 = qi[0], i1 = qi[1];
    int iy = g / WW;
    int ix = g - iy*WW;
    int iz = iy / HH; iy -= iz*HH;
    u64 fxm = fx(ix*(1.f/(WW-1)));
    u64 fdx = fx(1.f/(WW-1));
    u64 fym = fx(iy*(1.f/(HH-1)));
    u64 fzm = fx(iz*(1.f/(DD-1)));
    u32 cv8 = 0;
    size_t gi = (size_t)b*NV + g;
    if (mode == 0){
        int4 c0 = ((const int4*)&((const int*)cim)[gi])[0];
        int4 c1 = ((const int4*)&((const int*)cim)[gi])[1];
        cv8 = (c0.x?1u:0u)|(c0.y?2u:0u)|(c0.z?4u:0u)|(c0.w?8u:0u)
            | (c1.x?16u:0u)|(c1.y?32u:0u)|(c1.z?64u:0u)|(c1.w?128u:0u);
    } else if (mode == 1){
        u64 c = *(const u64*)&((const unsigned char*)cim)[gi];
        #pragma unroll
        for (int j = 0; j < 8; j++) if ((c >> (8*j)) & 0xFFull) cv8 |= 1u << j;
    } else if (mode == 2){
        float4 c0 = ((const float4*)&((const float*)cim)[gi])[0];
        float4 c1 = ((const float4*)&((const float*)cim)[gi])[1];
        cv8 = (c0.x!=0.f?1u:0u)|(c0.y!=0.f?2u:0u)|(c0.z!=0.f?4u:0u)|(c0.w!=0.f?8u:0u)
            | (c1.x!=0.f?16u:0u)|(c1.y!=0.f?32u:0u)|(c1.z!=0.f?64u:0u)|(c1.w!=0.f?128u:0u);
    } else {
        const int4* cc = (const int4*)&((const int*)cim)[2*gi];
        int4 c0 = cc[0], c1 = cc[1], c2 = cc[2], c3 = cc[3];
        cv8 = (c0.x?1u:0u)|(c0.z?2u:0u)|(c1.x?4u:0u)|(c1.z?8u:0u)
            | (c2.x?16u:0u)|(c2.z?32u:0u)|(c3.x?64u:0u)|(c3.z?128u:0u);
    }
    float s0a[8] = {sa0.x,sa0.y,sa0.z,sa0.w,sb0.x,sb0.y,sb0.z,sb0.w};
    float s1a[8] = {sa1.x,sa1.y,sa1.z,sa1.w,sb1.x,sb1.y,sb1.z,sb1.w};
    float s2a[8] = {sa2.x,sa2.y,sa2.z,sa2.w,sb2.x,sb2.y,sb2.z,sb2.w};
    int iva[8] = {i0.x,i0.y,i0.z,i0.w,i1.x,i1.y,i1.z,i1.w};
    #pragma unroll
    for (int j = 0; j < 8; j++){
        int iv = iva[j];
        if (iv >= 1 && iv <= KK){
            u64* bn = &bins[wv][lp][(iv-1)*3];
            u32 cv = (cv8 >> j) & 1u;
            u32 q0 = (u32)llrintf((s0a[j] + 16.f)*4096.f);
            u32 q1 = (u32)llrintf((s1a[j] + 16.f)*4096.f);
            u32 q2 = (u32)llrintf((s2a[j] + 16.f)*4096.f);
            float s2t = s0a[j]*s0a[j] + s1a[j]*s1a[j] + s2a[j]*s2a[j];
            u32 r = (u32)llrintf(fminf(s2t, 512.f)*2048.f);
            atomicAdd(&bn[0], (1ull << 44) | ((u64)(u32)(ix + j) << 24) | ((u64)(u32)iy << 4) | cv);
            atomicAdd(&bn[1], ((u64)q0 << 32) | q1);
            atomicAdd(&bn[2], ((u64)q2 << 32) | r);
            if (cv){
                u64* cb = &cmb[wv][iv-1][0];
                atomicAdd(&cb[0], fxm + (u64)j*fdx);
                atomicAdd(&cb[1], fym);
                atomicAdd(&cb[2], fzm);
            }
        }
    }
    __syncthreads();
    u64* cell0 = &ssh[((size_t)((sx&3)*BN + b))*KK*SSLOT];
    if (t < KK){
        int k = t;
        u64 sA = 0ull, sB = 0ull, sC = 0ull;
        #pragma unroll
        for (int r2 = 0; r2 < 32; r2++){
            const u64* bn = &bins[r2>>2][r2&3][k*3];
            sA += bn[0]; sB += bn[1]; sC += bn[2];
        }
        u64 cnt = sA >> 44;
        if (cnt){
            u64 six = (sA >> 24) & 0xFFFFFull;
            u64 siy = (sA >> 4) & 0xFFFFFull;
            u64 cm  = sA & 0xFull;
            long long bias = (long long)(cnt * 65536ull);   /* 16*4096 */
            long long g0 = (long long)(sB >> 32) - bias;
            long long g1 = (long long)(sB & 0xFFFFFFFFull) - bias;
            long long g2 = (long long)(sC >> 32) - bias;
            u64 h = sC & 0xFFFFFFFFull;
            u64* cell = cell0 + (size_t)k*SSLOT;
            atomicAdd(&cell[0], (cnt << 32) | cm);
            atomicAdd(&cell[1], six);
            atomicAdd(&cell[2], siy);
            atomicAdd(&cell[3], cnt*(u64)iz);
            atomicAdd(&cell[4], (u64)g0);
            atomicAdd(&cell[5], (u64)g1);
            atomicAdd(&cell[6], (u64)g2);
            atomicAdd(&cell[7], h);
        }
    }
    if (t < KK*3){
        int k = t / 3, s = t - k*3;
        u64 acc = 0ull;
        #pragma unroll
        for (int w = 0; w < 8; w++) acc += cmb[w][k][s];
        if (acc) atomicAdd(&cell0[(size_t)k*SSLOT + 8 + s], acc);
    }
    __syncthreads();
}

// ---------------- phase: hist tile (R13 body + prologue-derive) ----------------
__device__ __forceinline__ void do_hist_tile(int sx, int b, int t,
        const u64* __restrict__ ssh, const float* __restrict__ pred,
        const int* __restrict__ inst, const int* __restrict__ lab,
        u32* __restrict__ hs, u64* __restrict__ bgsh, u64* __restrict__ sm8){
    u32* lh = (u32*)sm8;                   /* 4096 u32 = 2048 u64 */
    float* dv = (float*)(sm8 + 2048);      /* 48 floats */
    u64* fgfx = sm8 + 2080;
    u64* bgfx = sm8 + 2081;
    if (t == 0){ *fgfx = 0ull; *bgfx = 0ull; }
    for (int i = t; i < KK*2*NB; i += 512) lh[i] = 0u;
    if (t < KK){
        int kq = t;
        Cell c = load_cell(ssh, b, kq);
        float safe = fmaxf(c.cnt, 1.f);
        float isafe = 1.f/safe;
        float c0 = (c.cmc == 1.f) ? c.cmx : c.mx*isafe;
        float c1 = (c.cmc == 1.f) ? c.cmy : c.my*isafe;
        float c2 = (c.cmc == 1.f) ? c.cmz : c.mz*isafe;
        dv[kq*6+0] = expf(10.f*c.g0*isafe)*L2E;
        dv[kq*6+1] = expf(10.f*c.g1*isafe)*L2E;
        dv[kq*6+2] = expf(10.f*c.g2*isafe)*L2E;
        dv[kq*6+3] = c0; dv[kq*6+4] = c1; dv[kq*6+5] = c2;
    }
    __syncthreads();
    float ax[KK], ay[KK], az[KK], cx[KK], cy[KK], cz[KK];
    #pragma unroll
    for (int k = 0; k < KK; k++){
        ax[k]=rfl(dv[k*6+0]); ay[k]=rfl(dv[k*6+1]); az[k]=rfl(dv[k*6+2]);
        cx[k]=rfl(dv[k*6+3]); cy[k]=rfl(dv[k*6+4]); cz[k]=rfl(dv[k*6+5]);
    }
    const float* pb = pred + (size_t)b*7*NV;
    const int* ib = inst + (size_t)b*NV;
    const int* lb = lab + (size_t)b*NV;
    int g = sx*VPB + t*8;
    const float4* q0 = (const float4*)&pb[g];
    const float4* q1 = (const float4*)&pb[(size_t)NV + g];
    const float4* q2 = (const float4*)&pb[2*(size_t)NV + g];
    const float4* q6 = (const float4*)&pb[6*(size_t)NV + g];
    float4 a0 = q0[0], b0 = q0[1];
    float4 a1 = q1[0], b1 = q1[1];
    float4 a2 = q2[0], b2 = q2[1];
    float4 a6 = q6[0], b6 = q6[1];
    const int4* qi = (const int4*)&ib[g];
    int4 i0 = qi[0], i1 = qi[1];
    const int4* ql = (const int4*)&lb[g];
    int4 l0 = ql[0], l1 = ql[1];
    int iy = g / WW;
    int ix = g - iy*WW;
    int iz = iy / HH; iy -= iz*HH;
    float xm = ix*(1.f/(WW-1)), ym = iy*(1.f/(HH-1)), zm = iz*(1.f/(DD-1));
    float p0a[8] = {a0.x,a0.y,a0.z,a0.w,b0.x,b0.y,b0.z,b0.w};
    float p1a[8] = {a1.x,a1.y,a1.z,a1.w,b1.x,b1.y,b1.z,b1.w};
    float p2a[8] = {a2.x,a2.y,a2.z,a2.w,b2.x,b2.y,b2.z,b2.w};
    float p6a[8] = {a6.x,a6.y,a6.z,a6.w,b6.x,b6.y,b6.z,b6.w};
    int iva[8] = {i0.x,i0.y,i0.z,i0.w,i1.x,i1.y,i1.z,i1.w};
    int lba[8] = {l0.x,l0.y,l0.z,l0.w,l1.x,l1.y,l1.z,l1.w};
    float e0[8], e1[8], e2[8], sd[8];
    float bgacc = 0.f;
    #pragma unroll
    for (int j = 0; j < 8; j++){
        e0[j] = tanh_f(p0a[j]) + xm + j*(1.f/(WW-1));
        e1[j] = tanh_f(p1a[j]) + ym;
        e2[j] = tanh_f(p2a[j]) + zm;
        sd[j] = sigm_f(p6a[j]);
        if (lba[j] == 0) bgacc += sd[j]*sd[j];
    }
    float fgacc = 0.f;
    #pragma unroll
    for (int k = 0; k < KK; k++){
        #pragma unroll
        for (int j = 0; j < 8; j++){
            float d0 = e0[j] - cx[k], d1 = e1[j] - cy[k], dz = e2[j] - cz[k];
            float d2 = ax[k]*d0*d0;
            d2 = fmaf(ay[k]*d1, d1, d2);
            d2 = fmaf(az[k]*dz, dz, d2);
            float dist = exp2_f(-d2);               /* L2E folded into a's */
            if (iva[j] == k + 1){
                float e = fmaf(-2.f, dist, 2.f);
                int bu = (int)(__float_as_uint(e) >> 19) - BOFF;
                bu = bu < 0 ? 0 : (bu > NB-1 ? NB-1 : bu);
                atomicAdd(&lh[k*512 + bu], 1u);
                fgacc += (sd[j] - dist)*(sd[j] - dist);
            } else {
                /* e = 2*dist: bits(2x)>>19 == (bits(x)>>19)+16 for normals */
                int bu = (int)(__float_as_uint(dist) >> 19) - (BOFF - 16);
                bu = bu < 0 ? 0 : (bu > NB-1 ? NB-1 : bu);
                atomicAdd(&lh[k*512 + NB + bu], 1u);
            }
        }
    }
    #pragma unroll
    for (int off = 32; off > 0; off >>= 1){
        fgacc += __shfl_down(fgacc, off);
        bgacc += __shfl_down(bgacc, off);
    }
    if ((t & 63) == 0){
        if (fgacc != 0.f) atomicAdd(fgfx, fx(fgacc));
        if (bgacc != 0.f) atomicAdd(bgfx, fx(bgacc));
    }
    __syncthreads();
    if (t == 0){
        if (*bgfx) atomicAdd(&bgsh[(size_t)b*8 + (sx&7)], *bgfx);
        if (*fgfx) atomicAdd(&bgsh[(size_t)(2+b)*8 + (sx&7)], *fgfx);
    }
    u32* out = hs + ((size_t)b*NSL + sx)*(KK*NB);
    for (int i = t; i < KK*NB; i += 512){
        int k = i >> 8, bu = i & 255;
        out[i] = (lh[k*512 + bu] << 16) | lh[k*512 + NB + bu];
    }
    __syncthreads();
}

// ---------------- phase: lovasz (512 threads) + prologue-derive + ticket final ----------------
__device__ __forceinline__ void do_lovasz(int bk, int t,
        const u32* __restrict__ hs, const u64* __restrict__ ssh,
        float* __restrict__ lov, const u64* __restrict__ bgsh,
        u32* __restrict__ counter, float* __restrict__ out, u64* __restrict__ sm8){
    int b = bk >> 3, k = bk & 7;
    u64 (*part)[NB] = (u64(*)[NB])sm8;         /* 512 u64 */
    u64* wsum = sm8 + 512;                      /* 4 u64 */
    float* racc = (float*)(sm8 + 516);          /* 256 floats = 128 u64 */
    float* s_cnt = (float*)(sm8 + 648);
    float* s_vrk = s_cnt + 16;
    float* s_val = s_cnt + 32;
    if (t < 16){
        Cell c = load_cell(ssh, t >> 3, t & 7);
        float safe = fmaxf(c.cnt, 1.f);
        float isafe = 1.f/safe;
        float sm0 = c.g0*isafe, sm1 = c.g1*isafe, sm2 = c.g2*isafe;
        float vs = c.h - 2.f*(sm0*c.g0 + sm1*c.g1 + sm2*c.g2)
                 + (sm0*sm0 + sm1*sm1 + sm2*sm2)*c.cnt;
        s_vrk[t] = vs*isafe*(1.f/3.f);
        s_val[t] = c.cnt > 0.f ? 1.f : 0.f;
        s_cnt[t] = c.cnt;
    }
    __syncthreads();
    float gts = s_cnt[bk];
    float obj = fmaxf(s_val[b*8+0]+s_val[b*8+1]+s_val[b*8+2]+s_val[b*8+3]
                     +s_val[b*8+4]+s_val[b*8+5]+s_val[b*8+6]+s_val[b*8+7], 1.f);
    float coef = s_val[bk]/obj;
    float lv = 0.f;
    if (gts >= 0.5f){
        int bu = (NB - 1) - (t & 255);    /* descending error order */
        int sg = t >> 8;                  /* 0..1 */
        u32 np = 0, nn = 0;
        const u32* base = hs + (size_t)b*NSL*(KK*NB) + k*NB + bu;
        for (int s = sg; s < NSL; s += 2){
            u32 h = base[(size_t)s*(KK*NB)];
            np += h >> 16; nn += h & 0xFFFFu;
        }
        part[sg][t & 255] = ((u64)np << 32) | nn;
        __syncthreads();
        u64 pack = 0ull, inc = 0ull;
        if (t < NB){
            pack = part[0][t] + part[1][t];
            int lane = t & 63;
            inc = pack;
            #pragma unroll
            for (int off = 1; off < 64; off <<= 1){
                u64 n = __shfl_up(inc, off);
                if (lane >= off) inc += n;
            }
            if (lane == 63) wsum[t >> 6] = inc;
        }
        __syncthreads();
        if (t < 4){
            u64 x = wsum[t];
            #pragma unroll
            for (int off = 1; off < 4; off <<= 1){
                u64 n = __shfl_up(x, off);
                if (t >= off) x += n;
            }
            wsum[t] = x;
        }
        __syncthreads();
        float acc = 0.f;
        if (t < NB){
            int wid = t >> 6;
            u64 excl = inc - pack + (wid ? wsum[wid - 1] : 0ull);
            u32 np2 = (u32)(pack >> 32), nn2 = (u32)pack;
            if (np2 | nn2){
                int bu2 = (NB - 1) - t;
                float Pe = (float)(u32)(excl >> 32), Qe = (float)(u32)excl;
                float Pi = Pe + (float)np2, Qi = Qe + (float)nn2;
                float je = 1.f - (gts - Pe)/(gts + Qe);
                float ji = 1.f - (gts - Pi)/(gts + Qi);
                u32 bits = ((u32)(bu2 + BOFF) << 19) | (1u << 18);
                if (bits > 0x40000000u) bits = 0x40000000u;
                acc = __uint_as_float(bits) * (ji - je);
            }
            racc[t] = acc;
        }
        __syncthreads();
        for (int off = 128; off > 0; off >>= 1){
            if (t < off) racc[t] += racc[t + off];
            __syncthreads();
        }
        lv = coef * racc[0];
    }
    if (t == 0){
        __hip_atomic_store(&lov[bk], lv, __ATOMIC_RELEASE, __HIP_MEMORY_SCOPE_AGENT);
        u32 ticket = __hip_atomic_fetch_add(counter, 1u, __ATOMIC_ACQ_REL, __HIP_MEMORY_SCOPE_AGENT);
        if (ticket == 15u){
            float tot = 0.f;
            for (int i = 0; i < 16; i++)
                tot += __hip_atomic_load(&lov[i], __ATOMIC_ACQUIRE, __HIP_MEMORY_SCOPE_AGENT);
            for (int b2 = 0; b2 < BN; b2++){
                float objb = fmaxf(s_val[b2*8+0]+s_val[b2*8+1]+s_val[b2*8+2]+s_val[b2*8+3]
                                  +s_val[b2*8+4]+s_val[b2*8+5]+s_val[b2*8+6]+s_val[b2*8+7], 1.f);
                float vp = 0.f;
                for (int kq = 0; kq < 8; kq++) vp += s_val[b2*8+kq]*s_vrk[b2*8+kq];
                float bg = 0.f, fg = 0.f;
                for (int sh = 0; sh < 8; sh++){
                    bg += unfx(bgsh[(size_t)b2*8 + sh]);
                    fg += unfx(bgsh[(size_t)(2+b2)*8 + sh]);
                }
                tot += 10.f*vp/objb + (bg + fg)*(1.f/(float)NV);
            }
            out[0] = tot * 0.5f;
        }
    }
}

// ================= cooperative mega-kernel: 1 dispatch =================
__global__ __launch_bounds__(512, 4) void k_mega(
        const float* __restrict__ pred, const int* __restrict__ inst,
        const int* __restrict__ lab, const void* __restrict__ cim,
        u64* __restrict__ ssh, u64* __restrict__ bgsh, u32* __restrict__ fpart,
        u32* __restrict__ hs, float* __restrict__ lov, u32* __restrict__ counter,
        float* __restrict__ out, int nzero_u64){
    cg::grid_group grid = cg::this_grid();
    __shared__ u64 sm8[SMU64];
    __shared__ u32 sfl;
    int bid = blockIdx.x, t = threadIdx.x;
    do_front(bid, t, (const u32*)cim, fpart, ssh, nzero_u64, counter, &sfl);
    grid.sync();
    int mode = decode_mode(t, fpart, &sfl);
    do_stats_tile(bid, 0, mode, t, pred, inst, cim, ssh, sm8);
    do_stats_tile(bid, 1, mode, t, pred, inst, cim, ssh, sm8);
    grid.sync();
    do_hist_tile(bid, 0, t, ssh, pred, inst, lab, hs, bgsh, sm8);
    do_hist_tile(bid, 1, t, ssh, pred, inst, lab, hs, bgsh, sm8);
    grid.sync();
    if (bid < 16) do_lovasz(bid, t, hs, ssh, lov, bgsh, counter, out, sm8);
}

// ================= fallback 4-dispatch path (R13-proven) =================
__global__ __launch_bounds__(512) void k_front(
        const u32* __restrict__ w, u32* __restrict__ fpart,
        u64* __restrict__ zero_base, int nzero_u64, u32* __restrict__ counter){
    __shared__ u32 sfl;
    do_front(blockIdx.x, threadIdx.x, w, fpart, zero_base, nzero_u64, counter, &sfl);
}

__global__ __launch_bounds__(512, 8) void k_stats(
        const float* __restrict__ pred, const int* __restrict__ inst,
        const void* __restrict__ cim, const u32* __restrict__ fpart,
        u64* __restrict__ ssh){
    __shared__ u64 sm8[1056];
    __shared__ u32 sfl;
    int mode = decode_mode(threadIdx.x, fpart, &sfl);
    do_stats_tile(blockIdx.x, blockIdx.y, mode, threadIdx.x, pred, inst, cim, ssh, sm8);
}

__global__ __launch_bounds__(512, 4) void k_hist(
        const u64* __restrict__ ssh, const float* __restrict__ pred,
        const int* __restrict__ inst, const int* __restrict__ lab,
        u32* __restrict__ hs, u64* __restrict__ bgsh){
    __shared__ u64 sm8[SMU64];
    do_hist_tile(blockIdx.x, blockIdx.y, threadIdx.x, ssh, pred, inst, lab, hs, bgsh, sm8);
}

__global__ __launch_bounds__(512) void k_lovasz(
        const u32* __restrict__ hs, const u64* __restrict__ ssh,
        float* __restrict__ lov, const u64* __restrict__ bgsh,
        u32* __restrict__ counter, float* __restrict__ out){
    __shared__ u64 sm8[800];
    do_lovasz(blockIdx.x, threadIdx.x, hs, ssh, lov, bgsh, counter, out, sm8);
}

extern "C" void kernel_launch(void* const* d_in, const int* in_sizes, int n_in,
                              void* d_out, int out_size, void* d_ws, size_t ws_size,
                              hipStream_t stream){
    const float* pred = (const float*)d_in[0];
    const int*   inst = (const int*)d_in[2];
    const int*   lab  = (const int*)d_in[3];
    const void*  cim  = d_in[4];
    float* outp = (float*)d_out;

    char* ws = (char*)d_ws;
    size_t off = 0;
    u32* hs = (u32*)(ws + off);        off += (size_t)BN*NSL*KK*NB*4;   /* 4.72 MB */
    size_t zero0 = off;
    u64* ssh = (u64*)(ws + off);       off += (size_t)4*BN*KK*SSLOT*8;  /* stat shards */
    u64* bgsh = (u64*)(ws + off);      off += (size_t)4*8*8;            /* bg/fg shards */
    int nzero_u64 = (int)((off - zero0)/8);
    float* lov = (float*)(ws + off);   off += 16*4;
    u32* counter = (u32*)(ws + off);   off += 4;
    u32* fpart = (u32*)(ws + off);     off += NBLK*4;

    void* kargs[] = {(void*)&pred, (void*)&inst, (void*)&lab, (void*)&cim,
                     (void*)&ssh, (void*)&bgsh, (void*)&fpart, (void*)&hs,
                     (void*)&lov, (void*)&counter, (void*)&outp, (void*)&nzero_u64};
    hipError_t e = hipLaunchCooperativeKernel(reinterpret_cast<void*>(k_mega),
                                              dim3(NBLK), dim3(512), kargs, 0, stream);
    if (e != hipSuccess){
        /* fallback: proven 4-dispatch pipeline */
        k_front<<<dim3(NBLK), dim3(512), 0, stream>>>((const u32*)cim, fpart, ssh, nzero_u64, counter);
        k_stats<<<dim3(NSL, BN), dim3(512), 0, stream>>>(pred, inst, cim, fpart, ssh);
        k_hist<<<dim3(NSL, BN), dim3(512), 0, stream>>>(ssh, pred, inst, lab, hs, bgsh);
        k_lovasz<<<16, 512, 0, stream>>>(hs, ssh, lov, bgsh, counter, outp);
    }
}

// Round 15
// 69.287 us; speedup vs baseline: 2.7058x; 2.7058x over previous
//
#include <hip/hip_runtime.h>
#include <stdint.h>

typedef unsigned long long u64;
typedef unsigned int u32;

#define BN 2
#define DD 32
#define HH 192
#define WW 192
#define NV (DD*HH*WW)   /* 1179648 */
#define KK 8
#define NSL 288         /* tiles per batch, 4096 vox each */
#define VPB 4096
#define NB 256          /* buckets in window */
#define BOFF 1808       /* 0x38800000>>19 : window floor e = 2^-14 */
#define L2E 1.44269504f
#define SSLOT 11
#define NFRONT 288

__device__ __forceinline__ u64 fx(float v){ return (u64)(long long)llrintf(v*4294967296.0f); }
__device__ __forceinline__ float unfx(u64 v){ return (float)((double)(long long)v*(1.0/4294967296.0)); }
__device__ __forceinline__ float rcp_f(float x){ return __builtin_amdgcn_rcpf(x); }
__device__ __forceinline__ float exp2_f(float x){ return __builtin_amdgcn_exp2f(x); }
__device__ __forceinline__ float tanh_f(float x){ return 1.f - 2.f*rcp_f(1.f + exp2_f(x*(2.f*L2E))); }
__device__ __forceinline__ float sigm_f(float x){ return rcp_f(1.f + exp2_f(-x*L2E)); }
__device__ __forceinline__ float rfl(float x){ return __uint_as_float(__builtin_amdgcn_readfirstlane((int)__float_as_uint(x))); }

// unpack cell (b,k) from 4 shards:
// 0 cnt<<32|cm, 1..3 Six/Siy/Siz, 4..6 Ssig*4096 (signed), 7 Ss2*2048, 8..10 cm fx32
struct Cell { float cnt, cmc, mx, my, mz, g0, g1, g2, h, cmx, cmy, cmz; };
__device__ __forceinline__ Cell load_cell(const u64* __restrict__ ssh, int bb, int kq){
    u64 st[SSLOT];
    #pragma unroll
    for (int s = 0; s < SSLOT; s++){
        u64 a = 0ull;
        #pragma unroll
        for (int sh = 0; sh < 4; sh++)
            a += ssh[((size_t)(sh*BN + bb)*KK + kq)*SSLOT + s];
        st[s] = a;
    }
    Cell c;
    c.cnt = (float)(long long)(st[0] >> 32);
    c.cmc = (float)(u32)st[0];
    c.mx = (float)(long long)st[1] * (1.f/(WW-1));
    c.my = (float)(long long)st[2] * (1.f/(HH-1));
    c.mz = (float)(long long)st[3] * (1.f/(DD-1));
    c.g0 = (float)((double)(long long)st[4] * (1.0/4096.0));
    c.g1 = (float)((double)(long long)st[5] * (1.0/4096.0));
    c.g2 = (float)((double)(long long)st[6] * (1.0/4096.0));
    c.h  = (float)((double)(long long)st[7] * (1.0/2048.0));
    c.cmx = unfx(st[8]); c.cmy = unfx(st[9]); c.cmz = unfx(st[10]);
    return c;
}

// ---------------- front: zero accumulators + detect cim layout ----------------
__global__ __launch_bounds__(512) void k_front(
        const u32* __restrict__ w, u32* __restrict__ fpart,
        u64* __restrict__ zero_base, int nzero_u64, u32* __restrict__ counter){
    int bid = blockIdx.x, t = threadIdx.x;
    if (bid == 0){
        for (int i = t; i < nzero_u64; i += 512) zero_base[i] = 0ull;
        if (t == 0) *counter = 0u;
    }
    __shared__ u32 sfl;
    if (t == 0) sfl = 0u;
    __syncthreads();
    const int chunk = (BN*NV/4)/NFRONT;   /* 2048 */
    u32 f = 0;
    for (int i = bid*chunk + t; i < (bid+1)*chunk; i += 512){
        u32 x = w[i];
        if (x == 0x3F800000u) f |= 1u;
        else if (x > 1u) f |= 2u;
        else if (x == 1u){ f |= 8u; if (i & 1) f |= 4u; }
    }
    if (f) atomicOr(&sfl, f);
    __syncthreads();
    if (t == 0) fpart[bid] = sfl;
}

// ---------------- mode decode from fpart (block prologue) ----------------
__device__ __forceinline__ int decode_mode(int t, int nthr, const u32* __restrict__ fpart,
                                           u32* __restrict__ sfl){
    if (t == 0) *sfl = 0u;
    __syncthreads();
    u32 fo = 0;
    for (int i = t; i < NFRONT; i += nthr) fo |= fpart[i];
    if (fo) atomicOr(sfl, fo);
    __syncthreads();
    u32 fl = *sfl;
    __syncthreads();
    return (fl & 1u) ? 2 : ((fl & 2u) ? 1 : ((fl & 4u) ? 0 : ((fl & 8u) ? 3 : 0)));
}

// ---------------- per-instance statistics: 1024 thr, 4 vox/thread ----------------
__global__ __launch_bounds__(1024, 8) void k_stats(
        const float* __restrict__ pred, const int* __restrict__ inst,
        const void* __restrict__ cim, const u32* __restrict__ fpart,
        u64* __restrict__ ssh){
    int sx = blockIdx.x, b = blockIdx.y;
    __shared__ u64 bins[16][4][25];      /* 64 replicas, stride 25: 12.8 KB */
    __shared__ u64 cmb[16][KK][4];       /* rare cm sums, per-wave: 4 KB */
    __shared__ u32 sfl;
    for (int i = threadIdx.x; i < 16*4*25; i += 1024) ((u64*)bins)[i] = 0ull;
    for (int i = threadIdx.x; i < 16*KK*4; i += 1024) ((u64*)cmb)[i] = 0ull;
    int mode = decode_mode(threadIdx.x, 1024, fpart, &sfl);
    const float* pb = pred + (size_t)b*7*NV;
    const int* ib = inst + (size_t)b*NV;
    int t = threadIdx.x;
    int wv = t >> 6, lp = t & 3;
    int g = sx*VPB + t*4;

    float4 s0v = *(const float4*)&pb[3*(size_t)NV + g];
    float4 s1v = *(const float4*)&pb[4*(size_t)NV + g];
    float4 s2v = *(const float4*)&pb[5*(size_t)NV + g];
    int4 iv4 = *(const int4*)&ib[g];
    int iy = g / WW;
    int ix = g - iy*WW;
    int iz = iy / HH; iy -= iz*HH;
    u64 fxm = fx(ix*(1.f/(WW-1)));
    u64 fdx = fx(1.f/(WW-1));
    u64 fym = fx(iy*(1.f/(HH-1)));
    u64 fzm = fx(iz*(1.f/(DD-1)));
    u32 cv4 = 0;
    size_t gi = (size_t)b*NV + g;
    if (mode == 0){
        int4 c = *(const int4*)&((const int*)cim)[gi];
        cv4 = (c.x?1u:0u)|(c.y?2u:0u)|(c.z?4u:0u)|(c.w?8u:0u);
    } else if (mode == 1){
        u32 c = *(const u32*)&((const unsigned char*)cim)[gi];
        cv4 = ((c&0xFFu)?1u:0u)|((c&0xFF00u)?2u:0u)|((c&0xFF0000u)?4u:0u)|((c&0xFF000000u)?8u:0u);
    } else if (mode == 2){
        float4 c = *(const float4*)&((const float*)cim)[gi];
        cv4 = (c.x!=0.f?1u:0u)|(c.y!=0.f?2u:0u)|(c.z!=0.f?4u:0u)|(c.w!=0.f?8u:0u);
    } else {
        int4 c0 = *(const int4*)&((const int*)cim)[2*gi];
        int4 c1 = *(const int4*)&((const int*)cim)[2*gi + 4];
        cv4 = (c0.x?1u:0u)|(c0.z?2u:0u)|(c1.x?4u:0u)|(c1.z?8u:0u);
    }
    float s0a[4] = {s0v.x,s0v.y,s0v.z,s0v.w};
    float s1a[4] = {s1v.x,s1v.y,s1v.z,s1v.w};
    float s2a[4] = {s2v.x,s2v.y,s2v.z,s2v.w};
    int iva[4] = {iv4.x,iv4.y,iv4.z,iv4.w};
    #pragma unroll
    for (int j = 0; j < 4; j++){
        int iv = iva[j];
        if (iv >= 1 && iv <= KK){
            u64* bn = &bins[wv][lp][(iv-1)*3];
            u32 cv = (cv4 >> j) & 1u;
            u32 q0 = (u32)llrintf((s0a[j] + 16.f)*4096.f);
            u32 q1 = (u32)llrintf((s1a[j] + 16.f)*4096.f);
            u32 q2 = (u32)llrintf((s2a[j] + 16.f)*4096.f);
            float s2t = s0a[j]*s0a[j] + s1a[j]*s1a[j] + s2a[j]*s2a[j];
            u32 r = (u32)llrintf(fminf(s2t, 512.f)*2048.f);
            atomicAdd(&bn[0], (1ull << 44) | ((u64)(u32)(ix + j) << 24) | ((u64)(u32)iy << 4) | cv);
            atomicAdd(&bn[1], ((u64)q0 << 32) | q1);
            atomicAdd(&bn[2], ((u64)q2 << 32) | r);
            if (cv){
                u64* cb = &cmb[wv][iv-1][0];
                atomicAdd(&cb[0], fxm + (u64)j*fdx);
                atomicAdd(&cb[1], fym);
                atomicAdd(&cb[2], fzm);
            }
        }
    }
    __syncthreads();
    u64* cell0 = &ssh[((size_t)((sx&3)*BN + b))*KK*SSLOT];
    if (t < KK){
        int k = t;
        u64 sA = 0ull, sB = 0ull, sC = 0ull;
        #pragma unroll
        for (int r2 = 0; r2 < 64; r2++){
            const u64* bn = &bins[r2>>2][r2&3][k*3];
            sA += bn[0]; sB += bn[1]; sC += bn[2];
        }
        u64 cnt = sA >> 44;
        if (cnt){
            u64 six = (sA >> 24) & 0xFFFFFull;
            u64 siy = (sA >> 4) & 0xFFFFFull;
            u64 cm  = sA & 0xFull;
            long long bias = (long long)(cnt * 65536ull);   /* 16*4096 */
            long long g0 = (long long)(sB >> 32) - bias;
            long long g1 = (long long)(sB & 0xFFFFFFFFull) - bias;
            long long g2 = (long long)(sC >> 32) - bias;
            u64 h = sC & 0xFFFFFFFFull;
            u64* cell = cell0 + (size_t)k*SSLOT;
            atomicAdd(&cell[0], (cnt << 32) | cm);
            atomicAdd(&cell[1], six);
            atomicAdd(&cell[2], siy);
            atomicAdd(&cell[3], cnt*(u64)iz);
            atomicAdd(&cell[4], (u64)g0);
            atomicAdd(&cell[5], (u64)g1);
            atomicAdd(&cell[6], (u64)g2);
            atomicAdd(&cell[7], h);
        }
    }
    if (t < KK*3){
        int k = t / 3, s = t - k*3;
        u64 acc = 0ull;
        #pragma unroll
        for (int w = 0; w < 16; w++) acc += cmb[w][k][s];
        if (acc) atomicAdd(&cell0[(size_t)k*SSLOT + 8 + s], acc);
    }
}

// ---------------- all-k windowed histogram + bg/fg seed + prologue-derive ----------------
__global__ __launch_bounds__(1024, 8) void k_hist(
        const u64* __restrict__ ssh, const float* __restrict__ pred,
        const int* __restrict__ inst, const int* __restrict__ lab,
        u32* __restrict__ hs, u64* __restrict__ bgsh){
    __shared__ u32 lh[KK*2*NB];   /* 16 KB */
    __shared__ u64 fgfx, bgfx;
    __shared__ float dv[KK*6];
    int sx = blockIdx.x, b = blockIdx.y;
    int t = threadIdx.x;
    if (t == 0){ fgfx = 0ull; bgfx = 0ull; }
    for (int i = t; i < KK*2*NB; i += 1024) lh[i] = 0u;
    if (t < KK){
        int kq = t;
        Cell c = load_cell(ssh, b, kq);
        float safe = fmaxf(c.cnt, 1.f);
        float isafe = 1.f/safe;
        float c0 = (c.cmc == 1.f) ? c.cmx : c.mx*isafe;
        float c1 = (c.cmc == 1.f) ? c.cmy : c.my*isafe;
        float c2 = (c.cmc == 1.f) ? c.cmz : c.mz*isafe;
        dv[kq*6+0] = expf(10.f*c.g0*isafe)*L2E;
        dv[kq*6+1] = expf(10.f*c.g1*isafe)*L2E;
        dv[kq*6+2] = expf(10.f*c.g2*isafe)*L2E;
        dv[kq*6+3] = c0; dv[kq*6+4] = c1; dv[kq*6+5] = c2;
    }
    __syncthreads();
    float ax[KK], ay[KK], az[KK], cx[KK], cy[KK], cz[KK];
    #pragma unroll
    for (int k = 0; k < KK; k++){
        ax[k]=rfl(dv[k*6+0]); ay[k]=rfl(dv[k*6+1]); az[k]=rfl(dv[k*6+2]);
        cx[k]=rfl(dv[k*6+3]); cy[k]=rfl(dv[k*6+4]); cz[k]=rfl(dv[k*6+5]);
    }
    const float* pb = pred + (size_t)b*7*NV;
    const int* ib = inst + (size_t)b*NV;
    const int* lb = lab + (size_t)b*NV;
    int g = sx*VPB + t*4;
    float4 p0 = *(const float4*)&pb[g];
    float4 p1 = *(const float4*)&pb[(size_t)NV + g];
    float4 p2 = *(const float4*)&pb[2*(size_t)NV + g];
    float4 p6 = *(const float4*)&pb[6*(size_t)NV + g];
    int4 iv4 = *(const int4*)&ib[g];
    int4 lb4 = *(const int4*)&lb[g];
    int iy = g / WW;
    int ix = g - iy*WW;
    int iz = iy / HH; iy -= iz*HH;
    float xm = ix*(1.f/(WW-1)), ym = iy*(1.f/(HH-1)), zm = iz*(1.f/(DD-1));
    float p0a[4] = {p0.x,p0.y,p0.z,p0.w};
    float p1a[4] = {p1.x,p1.y,p1.z,p1.w};
    float p2a[4] = {p2.x,p2.y,p2.z,p2.w};
    float p6a[4] = {p6.x,p6.y,p6.z,p6.w};
    int iva[4] = {iv4.x,iv4.y,iv4.z,iv4.w};
    int lba[4] = {lb4.x,lb4.y,lb4.z,lb4.w};
    float e0[4], e1[4], e2[4], sd[4];
    float bgacc = 0.f;
    #pragma unroll
    for (int j = 0; j < 4; j++){
        e0[j] = tanh_f(p0a[j]) + xm + j*(1.f/(WW-1));
        e1[j] = tanh_f(p1a[j]) + ym;
        e2[j] = tanh_f(p2a[j]) + zm;
        sd[j] = sigm_f(p6a[j]);
        if (lba[j] == 0) bgacc += sd[j]*sd[j];
    }
    float fgacc = 0.f;
    #pragma unroll
    for (int k = 0; k < KK; k++){
        #pragma unroll
        for (int j = 0; j < 4; j++){
            float d0 = e0[j] - cx[k], d1 = e1[j] - cy[k], dz = e2[j] - cz[k];
            float d2 = ax[k]*d0*d0;
            d2 = fmaf(ay[k]*d1, d1, d2);
            d2 = fmaf(az[k]*dz, dz, d2);
            float dist = exp2_f(-d2);               /* L2E folded into a's */
            if (iva[j] == k + 1){
                float e = fmaf(-2.f, dist, 2.f);
                int bu = (int)(__float_as_uint(e) >> 19) - BOFF;
                bu = bu < 0 ? 0 : (bu > NB-1 ? NB-1 : bu);
                atomicAdd(&lh[k*512 + bu], 1u);
                fgacc += (sd[j] - dist)*(sd[j] - dist);
            } else {
                /* e = 2*dist: bits(2x)>>19 == (bits(x)>>19)+16 for normals */
                int bu = (int)(__float_as_uint(dist) >> 19) - (BOFF - 16);
                bu = bu < 0 ? 0 : (bu > NB-1 ? NB-1 : bu);
                atomicAdd(&lh[k*512 + NB + bu], 1u);
            }
        }
    }
    #pragma unroll
    for (int off = 32; off > 0; off >>= 1){
        fgacc += __shfl_down(fgacc, off);
        bgacc += __shfl_down(bgacc, off);
    }
    if ((t & 63) == 0){
        if (fgacc != 0.f) atomicAdd(&fgfx, fx(fgacc));
        if (bgacc != 0.f) atomicAdd(&bgfx, fx(bgacc));
    }
    __syncthreads();
    if (t == 0){
        if (bgfx) atomicAdd(&bgsh[(size_t)b*8 + (sx&7)], bgfx);
        if (fgfx) atomicAdd(&bgsh[(size_t)(2+b)*8 + (sx&7)], fgfx);
    }
    u32* out = hs + ((size_t)b*NSL + sx)*(KK*NB);
    for (int i = t; i < KK*NB; i += 1024){
        int k = i >> 8, bu = i & 255;
        out[i] = (lh[k*512 + bu] << 16) | lh[k*512 + NB + bu];
    }
}

// ---------------- Lovasz scan + prologue-derive + fused final (16 blocks) ----------------
__global__ __launch_bounds__(1024) void k_lovasz(
        const u32* __restrict__ hs, const u64* __restrict__ ssh,
        float* __restrict__ lov, const u64* __restrict__ bgsh,
        u32* __restrict__ counter, float* __restrict__ out){
    int bk = blockIdx.x, b = bk >> 3, k = bk & 7;
    int t = threadIdx.x;
    __shared__ float s_cnt[16], s_vrk[16], s_val[16];
    if (t < 16){
        Cell c = load_cell(ssh, t >> 3, t & 7);
        float safe = fmaxf(c.cnt, 1.f);
        float isafe = 1.f/safe;
        float sm0 = c.g0*isafe, sm1 = c.g1*isafe, sm2 = c.g2*isafe;
        float vs = c.h - 2.f*(sm0*c.g0 + sm1*c.g1 + sm2*c.g2)
                 + (sm0*sm0 + sm1*sm1 + sm2*sm2)*c.cnt;
        s_vrk[t] = vs*isafe*(1.f/3.f);
        s_val[t] = c.cnt > 0.f ? 1.f : 0.f;
        s_cnt[t] = c.cnt;
    }
    __syncthreads();
    float gts = s_cnt[bk];
    float obj = fmaxf(s_val[b*8+0]+s_val[b*8+1]+s_val[b*8+2]+s_val[b*8+3]
                     +s_val[b*8+4]+s_val[b*8+5]+s_val[b*8+6]+s_val[b*8+7], 1.f);
    float coef = s_val[bk]/obj;
    float lv = 0.f;
    __shared__ u64 part[4][NB];
    __shared__ u64 wsum[4];
    __shared__ float racc[NB];
    if (gts >= 0.5f){
        int bu = (NB - 1) - (t & 255);    /* descending error order */
        int sg = t >> 8;
        u32 np = 0, nn = 0;
        const u32* base = hs + (size_t)b*NSL*(KK*NB) + k*NB + bu;
        for (int s = sg; s < NSL; s += 4){
            u32 h = base[(size_t)s*(KK*NB)];
            np += h >> 16; nn += h & 0xFFFFu;
        }
        part[sg][t & 255] = ((u64)np << 32) | nn;
        __syncthreads();
        u64 pack = 0ull, inc = 0ull;
        if (t < NB){
            pack = part[0][t] + part[1][t] + part[2][t] + part[3][t];
            int lane = t & 63;
            inc = pack;
            #pragma unroll
            for (int off = 1; off < 64; off <<= 1){
                u64 n = __shfl_up(inc, off);
                if (lane >= off) inc += n;
            }
            if (lane == 63) wsum[t >> 6] = inc;
        }
        __syncthreads();
        if (t < 4){
            u64 x = wsum[t];
            #pragma unroll
            for (int off = 1; off < 4; off <<= 1){
                u64 n = __shfl_up(x, off);
                if (t >= off) x += n;
            }
            wsum[t] = x;
        }
        __syncthreads();
        float acc = 0.f;
        if (t < NB){
            int wid = t >> 6;
            u64 excl = inc - pack + (wid ? wsum[wid - 1] : 0ull);
            u32 np2 = (u32)(pack >> 32), nn2 = (u32)pack;
            if (np2 | nn2){
                int bu2 = (NB - 1) - t;
                float Pe = (float)(u32)(excl >> 32), Qe = (float)(u32)excl;
                float Pi = Pe + (float)np2, Qi = Qe + (float)nn2;
                float je = 1.f - (gts - Pe)/(gts + Qe);
                float ji = 1.f - (gts - Pi)/(gts + Qi);
                u32 bits = ((u32)(bu2 + BOFF) << 19) | (1u << 18);
                if (bits > 0x40000000u) bits = 0x40000000u;
                acc = __uint_as_float(bits) * (ji - je);
            }
            racc[t] = acc;
        }
        __syncthreads();
        for (int off = 128; off > 0; off >>= 1){
            if (t < off) racc[t] += racc[t + off];
            __syncthreads();
        }
        lv = coef * racc[0];
    }
    if (t == 0){
        __hip_atomic_store(&lov[bk], lv, __ATOMIC_RELEASE, __HIP_MEMORY_SCOPE_AGENT);
        u32 ticket = __hip_atomic_fetch_add(counter, 1u, __ATOMIC_ACQ_REL, __HIP_MEMORY_SCOPE_AGENT);
        if (ticket == 15u){
            float tot = 0.f;
            for (int i = 0; i < 16; i++)
                tot += __hip_atomic_load(&lov[i], __ATOMIC_ACQUIRE, __HIP_MEMORY_SCOPE_AGENT);
            for (int b2 = 0; b2 < BN; b2++){
                float objb = fmaxf(s_val[b2*8+0]+s_val[b2*8+1]+s_val[b2*8+2]+s_val[b2*8+3]
                                  +s_val[b2*8+4]+s_val[b2*8+5]+s_val[b2*8+6]+s_val[b2*8+7], 1.f);
                float vp = 0.f;
                for (int kq = 0; kq < 8; kq++) vp += s_val[b2*8+kq]*s_vrk[b2*8+kq];
                float bg = 0.f, fg = 0.f;
                for (int sh = 0; sh < 8; sh++){
                    bg += unfx(bgsh[(size_t)b2*8 + sh]);
                    fg += unfx(bgsh[(size_t)(2+b2)*8 + sh]);
                }
                tot += 10.f*vp/objb + (bg + fg)*(1.f/(float)NV);
            }
            out[0] = tot * 0.5f;
        }
    }
}

extern "C" void kernel_launch(void* const* d_in, const int* in_sizes, int n_in,
                              void* d_out, int out_size, void* d_ws, size_t ws_size,
                              hipStream_t stream){
    const float* pred = (const float*)d_in[0];
    const int*   inst = (const int*)d_in[2];
    const int*   lab  = (const int*)d_in[3];
    const void*  cim  = d_in[4];

    char* ws = (char*)d_ws;
    size_t off = 0;
    u32* hs = (u32*)(ws + off);        off += (size_t)BN*NSL*KK*NB*4;   /* 4.72 MB */
    size_t zero0 = off;
    u64* ssh = (u64*)(ws + off);       off += (size_t)4*BN*KK*SSLOT*8;  /* stat shards */
    u64* bgsh = (u64*)(ws + off);      off += (size_t)4*8*8;            /* bg/fg shards */
    int nzero_u64 = (int)((off - zero0)/8);
    float* lov = (float*)(ws + off);   off += 16*4;
    u32* counter = (u32*)(ws + off);   off += 4;
    u32* fpart = (u32*)(ws + off);     off += NFRONT*4;

    k_front<<<dim3(NFRONT), dim3(512), 0, stream>>>((const u32*)cim, fpart, ssh, nzero_u64, counter);
    k_stats<<<dim3(NSL, BN), dim3(1024), 0, stream>>>(pred, inst, cim, fpart, ssh);
    k_hist<<<dim3(NSL, BN), dim3(1024), 0, stream>>>(ssh, pred, inst, lab, hs, bgsh);
    k_lovasz<<<16, 1024, 0, stream>>>(hs, ssh, lov, bgsh, counter, (float*)d_out);
}

// Round 16
// 67.571 us; speedup vs baseline: 2.7746x; 1.0254x over previous
//
#include <hip/hip_runtime.h>
#include <stdint.h>

typedef unsigned long long u64;
typedef unsigned int u32;

#define BN 2
#define DD 32
#define HH 192
#define WW 192
#define NV (DD*HH*WW)   /* 1179648 */
#define KK 8
#define NSL 288         /* tiles per batch, 4096 vox each */
#define VPB 4096
#define NB 256          /* buckets in window */
#define BOFF 1808       /* 0x38800000>>19 : window floor e = 2^-14 */
#define L2E 1.44269504f
#define SSLOT 11
#define NFRONT 288

__device__ __forceinline__ u64 fx(float v){ return (u64)(long long)llrintf(v*4294967296.0f); }
__device__ __forceinline__ float unfx(u64 v){ return (float)((double)(long long)v*(1.0/4294967296.0)); }
__device__ __forceinline__ float rcp_f(float x){ return __builtin_amdgcn_rcpf(x); }
__device__ __forceinline__ float exp2_f(float x){ return __builtin_amdgcn_exp2f(x); }
__device__ __forceinline__ float tanh_f(float x){ return 1.f - 2.f*rcp_f(1.f + exp2_f(x*(2.f*L2E))); }
__device__ __forceinline__ float sigm_f(float x){ return rcp_f(1.f + exp2_f(-x*L2E)); }
__device__ __forceinline__ float rfl(float x){ return __uint_as_float(__builtin_amdgcn_readfirstlane((int)__float_as_uint(x))); }

// unpack cell (b,k) from 4 shards:
// 0 cnt<<32|cm, 1..3 Six/Siy/Siz, 4..6 Ssig*4096 (signed), 7 Ss2*2048, 8..10 cm fx32
struct Cell { float cnt, cmc, mx, my, mz, g0, g1, g2, h, cmx, cmy, cmz; };
__device__ __forceinline__ Cell load_cell(const u64* __restrict__ ssh, int bb, int kq){
    u64 st[SSLOT];
    #pragma unroll
    for (int s = 0; s < SSLOT; s++){
        u64 a = 0ull;
        #pragma unroll
        for (int sh = 0; sh < 4; sh++)
            a += ssh[((size_t)(sh*BN + bb)*KK + kq)*SSLOT + s];
        st[s] = a;
    }
    Cell c;
    c.cnt = (float)(long long)(st[0] >> 32);
    c.cmc = (float)(u32)st[0];
    c.mx = (float)(long long)st[1] * (1.f/(WW-1));
    c.my = (float)(long long)st[2] * (1.f/(HH-1));
    c.mz = (float)(long long)st[3] * (1.f/(DD-1));
    c.g0 = (float)((double)(long long)st[4] * (1.0/4096.0));
    c.g1 = (float)((double)(long long)st[5] * (1.0/4096.0));
    c.g2 = (float)((double)(long long)st[6] * (1.0/4096.0));
    c.h  = (float)((double)(long long)st[7] * (1.0/2048.0));
    c.cmx = unfx(st[8]); c.cmy = unfx(st[9]); c.cmz = unfx(st[10]);
    return c;
}

// ---------------- front: zero accumulators (blocks 0..15) + detect cim layout ----------------
__global__ __launch_bounds__(512) void k_front(
        const u32* __restrict__ w, u32* __restrict__ fpart,
        u64* __restrict__ zero_base, int nzero_u64, u32* __restrict__ counter){
    int bid = blockIdx.x, t = threadIdx.x;
    if (bid < 16){
        int nz16 = (nzero_u64 + 15) >> 4;
        int lo = bid*nz16, hi = min(lo + nz16, nzero_u64);
        for (int i = lo + t; i < hi; i += 512) zero_base[i] = 0ull;
        if (bid == 0 && t == 0) *counter = 0u;
    }
    __shared__ u32 sfl;
    if (t == 0) sfl = 0u;
    __syncthreads();
    const int chunk = (BN*NV/4)/NFRONT;   /* 2048 */
    u32 f = 0;
    for (int i = bid*chunk + t; i < (bid+1)*chunk; i += 512){
        u32 x = w[i];
        if (x == 0x3F800000u) f |= 1u;
        else if (x > 1u) f |= 2u;
        else if (x == 1u){ f |= 8u; if (i & 1) f |= 4u; }
    }
    if (f) atomicOr(&sfl, f);
    __syncthreads();
    if (t == 0) fpart[bid] = sfl;
}

// ---------------- mode decode from fpart (block prologue) ----------------
__device__ __forceinline__ int decode_mode(int t, int nthr, const u32* __restrict__ fpart,
                                           u32* __restrict__ sfl){
    if (t == 0) *sfl = 0u;
    __syncthreads();
    u32 fo = 0;
    for (int i = t; i < NFRONT; i += nthr) fo |= fpart[i];
    if (fo) atomicOr(sfl, fo);
    __syncthreads();
    u32 fl = *sfl;
    __syncthreads();
    return (fl & 1u) ? 2 : ((fl & 2u) ? 1 : ((fl & 4u) ? 0 : ((fl & 8u) ? 3 : 0)));
}

// ---------------- per-instance statistics: 1024 thr, 4 vox/thread (R15-proven) ----------------
__global__ __launch_bounds__(1024, 8) void k_stats(
        const float* __restrict__ pred, const int* __restrict__ inst,
        const void* __restrict__ cim, const u32* __restrict__ fpart,
        u64* __restrict__ ssh){
    int sx = blockIdx.x, b = blockIdx.y;
    __shared__ u64 bins[16][4][25];      /* 64 replicas, stride 25: 12.8 KB */
    __shared__ u64 cmb[16][KK][4];       /* rare cm sums, per-wave: 4 KB */
    __shared__ u32 sfl;
    for (int i = threadIdx.x; i < 16*4*25; i += 1024) ((u64*)bins)[i] = 0ull;
    for (int i = threadIdx.x; i < 16*KK*4; i += 1024) ((u64*)cmb)[i] = 0ull;
    int mode = decode_mode(threadIdx.x, 1024, fpart, &sfl);
    const float* pb = pred + (size_t)b*7*NV;
    const int* ib = inst + (size_t)b*NV;
    int t = threadIdx.x;
    int wv = t >> 6, lp = t & 3;
    int g = sx*VPB + t*4;

    float4 s0v = *(const float4*)&pb[3*(size_t)NV + g];
    float4 s1v = *(const float4*)&pb[4*(size_t)NV + g];
    float4 s2v = *(const float4*)&pb[5*(size_t)NV + g];
    int4 iv4 = *(const int4*)&ib[g];
    int iy = g / WW;
    int ix = g - iy*WW;
    int iz = iy / HH; iy -= iz*HH;
    u64 fxm = fx(ix*(1.f/(WW-1)));
    u64 fdx = fx(1.f/(WW-1));
    u64 fym = fx(iy*(1.f/(HH-1)));
    u64 fzm = fx(iz*(1.f/(DD-1)));
    u32 cv4 = 0;
    size_t gi = (size_t)b*NV + g;
    if (mode == 0){
        int4 c = *(const int4*)&((const int*)cim)[gi];
        cv4 = (c.x?1u:0u)|(c.y?2u:0u)|(c.z?4u:0u)|(c.w?8u:0u);
    } else if (mode == 1){
        u32 c = *(const u32*)&((const unsigned char*)cim)[gi];
        cv4 = ((c&0xFFu)?1u:0u)|((c&0xFF00u)?2u:0u)|((c&0xFF0000u)?4u:0u)|((c&0xFF000000u)?8u:0u);
    } else if (mode == 2){
        float4 c = *(const float4*)&((const float*)cim)[gi];
        cv4 = (c.x!=0.f?1u:0u)|(c.y!=0.f?2u:0u)|(c.z!=0.f?4u:0u)|(c.w!=0.f?8u:0u);
    } else {
        int4 c0 = *(const int4*)&((const int*)cim)[2*gi];
        int4 c1 = *(const int4*)&((const int*)cim)[2*gi + 4];
        cv4 = (c0.x?1u:0u)|(c0.z?2u:0u)|(c1.x?4u:0u)|(c1.z?8u:0u);
    }
    float s0a[4] = {s0v.x,s0v.y,s0v.z,s0v.w};
    float s1a[4] = {s1v.x,s1v.y,s1v.z,s1v.w};
    float s2a[4] = {s2v.x,s2v.y,s2v.z,s2v.w};
    int iva[4] = {iv4.x,iv4.y,iv4.z,iv4.w};
    #pragma unroll
    for (int j = 0; j < 4; j++){
        int iv = iva[j];
        if (iv >= 1 && iv <= KK){
            u64* bn = &bins[wv][lp][(iv-1)*3];
            u32 cv = (cv4 >> j) & 1u;
            u32 q0 = (u32)llrintf((s0a[j] + 16.f)*4096.f);
            u32 q1 = (u32)llrintf((s1a[j] + 16.f)*4096.f);
            u32 q2 = (u32)llrintf((s2a[j] + 16.f)*4096.f);
            float s2t = s0a[j]*s0a[j] + s1a[j]*s1a[j] + s2a[j]*s2a[j];
            u32 r = (u32)llrintf(fminf(s2t, 512.f)*2048.f);
            atomicAdd(&bn[0], (1ull << 44) | ((u64)(u32)(ix + j) << 24) | ((u64)(u32)iy << 4) | cv);
            atomicAdd(&bn[1], ((u64)q0 << 32) | q1);
            atomicAdd(&bn[2], ((u64)q2 << 32) | r);
            if (cv){
                u64* cb = &cmb[wv][iv-1][0];
                atomicAdd(&cb[0], fxm + (u64)j*fdx);
                atomicAdd(&cb[1], fym);
                atomicAdd(&cb[2], fzm);
            }
        }
    }
    __syncthreads();
    u64* cell0 = &ssh[((size_t)((sx&3)*BN + b))*KK*SSLOT];
    if (t < KK){
        int k = t;
        u64 sA = 0ull, sB = 0ull, sC = 0ull;
        #pragma unroll
        for (int r2 = 0; r2 < 64; r2++){
            const u64* bn = &bins[r2>>2][r2&3][k*3];
            sA += bn[0]; sB += bn[1]; sC += bn[2];
        }
        u64 cnt = sA >> 44;
        if (cnt){
            u64 six = (sA >> 24) & 0xFFFFFull;
            u64 siy = (sA >> 4) & 0xFFFFFull;
            u64 cm  = sA & 0xFull;
            long long bias = (long long)(cnt * 65536ull);   /* 16*4096 */
            long long g0 = (long long)(sB >> 32) - bias;
            long long g1 = (long long)(sB & 0xFFFFFFFFull) - bias;
            long long g2 = (long long)(sC >> 32) - bias;
            u64 h = sC & 0xFFFFFFFFull;
            u64* cell = cell0 + (size_t)k*SSLOT;
            atomicAdd(&cell[0], (cnt << 32) | cm);
            atomicAdd(&cell[1], six);
            atomicAdd(&cell[2], siy);
            atomicAdd(&cell[3], cnt*(u64)iz);
            atomicAdd(&cell[4], (u64)g0);
            atomicAdd(&cell[5], (u64)g1);
            atomicAdd(&cell[6], (u64)g2);
            atomicAdd(&cell[7], h);
        }
    }
    if (t < KK*3){
        int k = t / 3, s = t - k*3;
        u64 acc = 0ull;
        #pragma unroll
        for (int w = 0; w < 16; w++) acc += cmb[w][k][s];
        if (acc) atomicAdd(&cell0[(size_t)k*SSLOT + 8 + s], acc);
    }
}

// ---------------- all-k windowed histogram: wave-uniform far-path + global ph merge ----------------
// ph[shard4][bk16][2*NB] u32; pos buckets [0,NB), neg [NB,2NB)
__global__ __launch_bounds__(1024, 8) void k_hist(
        const u64* __restrict__ ssh, const float* __restrict__ pred,
        const int* __restrict__ inst, const int* __restrict__ lab,
        u32* __restrict__ ph, u64* __restrict__ bgsh){
    __shared__ u32 lh[KK*2*NB];   /* 16 KB */
    __shared__ u64 fgfx, bgfx;
    __shared__ float dv[KK*6];
    int sx = blockIdx.x, b = blockIdx.y;
    int t = threadIdx.x;
    if (t == 0){ fgfx = 0ull; bgfx = 0ull; }
    for (int i = t; i < KK*2*NB; i += 1024) lh[i] = 0u;
    if (t < KK){
        int kq = t;
        Cell c = load_cell(ssh, b, kq);
        float safe = fmaxf(c.cnt, 1.f);
        float isafe = 1.f/safe;
        float c0 = (c.cmc == 1.f) ? c.cmx : c.mx*isafe;
        float c1 = (c.cmc == 1.f) ? c.cmy : c.my*isafe;
        float c2 = (c.cmc == 1.f) ? c.cmz : c.mz*isafe;
        dv[kq*6+0] = expf(10.f*c.g0*isafe)*L2E;
        dv[kq*6+1] = expf(10.f*c.g1*isafe)*L2E;
        dv[kq*6+2] = expf(10.f*c.g2*isafe)*L2E;
        dv[kq*6+3] = c0; dv[kq*6+4] = c1; dv[kq*6+5] = c2;
    }
    __syncthreads();
    float ax[KK], ay[KK], az[KK], cx[KK], cy[KK], cz[KK];
    #pragma unroll
    for (int k = 0; k < KK; k++){
        ax[k]=rfl(dv[k*6+0]); ay[k]=rfl(dv[k*6+1]); az[k]=rfl(dv[k*6+2]);
        cx[k]=rfl(dv[k*6+3]); cy[k]=rfl(dv[k*6+4]); cz[k]=rfl(dv[k*6+5]);
    }
    const float* pb = pred + (size_t)b*7*NV;
    const int* ib = inst + (size_t)b*NV;
    const int* lb = lab + (size_t)b*NV;
    int g = sx*VPB + t*4;
    float4 p0 = *(const float4*)&pb[g];
    float4 p1 = *(const float4*)&pb[(size_t)NV + g];
    float4 p2 = *(const float4*)&pb[2*(size_t)NV + g];
    float4 p6 = *(const float4*)&pb[6*(size_t)NV + g];
    int4 iv4 = *(const int4*)&ib[g];
    int4 lb4 = *(const int4*)&lb[g];
    int iy = g / WW;
    int ix = g - iy*WW;
    int iz = iy / HH; iy -= iz*HH;
    float xm = ix*(1.f/(WW-1)), ym = iy*(1.f/(HH-1)), zm = iz*(1.f/(DD-1));
    float p0a[4] = {p0.x,p0.y,p0.z,p0.w};
    float p1a[4] = {p1.x,p1.y,p1.z,p1.w};
    float p2a[4] = {p2.x,p2.y,p2.z,p2.w};
    float p6a[4] = {p6.x,p6.y,p6.z,p6.w};
    int iva[4] = {iv4.x,iv4.y,iv4.z,iv4.w};
    int lba[4] = {lb4.x,lb4.y,lb4.z,lb4.w};
    float e0[4], e1[4], e2[4], sd[4];
    float bgacc = 0.f;
    #pragma unroll
    for (int j = 0; j < 4; j++){
        e0[j] = tanh_f(p0a[j]) + xm + j*(1.f/(WW-1));
        e1[j] = tanh_f(p1a[j]) + ym;
        e2[j] = tanh_f(p2a[j]) + zm;
        sd[j] = sigm_f(p6a[j]);
        if (lba[j] == 0) bgacc += sd[j]*sd[j];
    }
    float fgacc = 0.f;
    #pragma unroll
    for (int k = 0; k < KK; k++){
        float d2L[4];
        #pragma unroll
        for (int j = 0; j < 4; j++){
            float d0 = e0[j] - cx[k], d1 = e1[j] - cy[k], dz = e2[j] - cz[k];
            float d2 = ax[k]*d0*d0;
            d2 = fmaf(ay[k]*d1, d1, d2);
            d2 = fmaf(az[k]*dz, dz, d2);
            d2L[j] = d2;        /* in log2 units (L2E folded into a's) */
        }
        bool anymask = (iva[0] == k+1) | (iva[1] == k+1) | (iva[2] == k+1) | (iva[3] == k+1);
        float dmin = fminf(fminf(d2L[0], d2L[1]), fminf(d2L[2], d2L[3]));
        bool fast = (dmin > 15.f) && !anymask;   /* all 4 -> neg bucket 0 exactly */
        if (__all(fast)){
            if ((t & 63) == 0) atomicAdd(&lh[k*512 + NB], 256u);
        } else {
            #pragma unroll
            for (int j = 0; j < 4; j++){
                float dist = exp2_f(-d2L[j]);
                if (iva[j] == k + 1){
                    float e = fmaf(-2.f, dist, 2.f);
                    int bu = (int)(__float_as_uint(e) >> 19) - BOFF;
                    bu = bu < 0 ? 0 : (bu > NB-1 ? NB-1 : bu);
                    atomicAdd(&lh[k*512 + bu], 1u);
                    fgacc += (sd[j] - dist)*(sd[j] - dist);
                } else {
                    /* e = 2*dist: bits(2x)>>19 == (bits(x)>>19)+16 for normals */
                    int bu = (int)(__float_as_uint(dist) >> 19) - (BOFF - 16);
                    bu = bu < 0 ? 0 : (bu > NB-1 ? NB-1 : bu);
                    atomicAdd(&lh[k*512 + NB + bu], 1u);
                }
            }
        }
    }
    #pragma unroll
    for (int off = 32; off > 0; off >>= 1){
        fgacc += __shfl_down(fgacc, off);
        bgacc += __shfl_down(bgacc, off);
    }
    if ((t & 63) == 0){
        if (fgacc != 0.f) atomicAdd(&fgfx, fx(fgacc));
        if (bgacc != 0.f) atomicAdd(&bgfx, fx(bgacc));
    }
    __syncthreads();
    if (t == 0){
        if (bgfx) atomicAdd(&bgsh[(size_t)b*8 + (sx&7)], bgfx);
        if (fgfx) atomicAdd(&bgsh[(size_t)(2+b)*8 + (sx&7)], fgfx);
    }
    /* merge non-zero buckets straight into sharded global hist */
    u32* phb = ph + ((size_t)(sx&3)*16 + (size_t)b*KK)*2*NB;
    for (int i = t; i < KK*2*NB; i += 1024){
        u32 v = lh[i];
        if (v){
            int k = i >> 9, rem = i & 511;
            atomicAdd(&phb[(size_t)k*2*NB + rem], v);
        }
    }
}

// ---------------- Lovasz scan over ph + prologue-derive + fused final (16x256) ----------------
__global__ __launch_bounds__(256) void k_lovasz(
        const u32* __restrict__ ph, const u64* __restrict__ ssh,
        float* __restrict__ lov, const u64* __restrict__ bgsh,
        u32* __restrict__ counter, float* __restrict__ out){
    int bk = blockIdx.x, b = bk >> 3;
    int t = threadIdx.x;
    __shared__ float s_cnt[16], s_vrk[16], s_val[16];
    if (t < 16){
        Cell c = load_cell(ssh, t >> 3, t & 7);
        float safe = fmaxf(c.cnt, 1.f);
        float isafe = 1.f/safe;
        float sm0 = c.g0*isafe, sm1 = c.g1*isafe, sm2 = c.g2*isafe;
        float vs = c.h - 2.f*(sm0*c.g0 + sm1*c.g1 + sm2*c.g2)
                 + (sm0*sm0 + sm1*sm1 + sm2*sm2)*c.cnt;
        s_vrk[t] = vs*isafe*(1.f/3.f);
        s_val[t] = c.cnt > 0.f ? 1.f : 0.f;
        s_cnt[t] = c.cnt;
    }
    __syncthreads();
    float gts = s_cnt[bk];
    float obj = fmaxf(s_val[b*8+0]+s_val[b*8+1]+s_val[b*8+2]+s_val[b*8+3]
                     +s_val[b*8+4]+s_val[b*8+5]+s_val[b*8+6]+s_val[b*8+7], 1.f);
    float coef = s_val[bk]/obj;
    float lv = 0.f;
    __shared__ u64 wsum[4];
    __shared__ float racc[NB];
    if (gts >= 0.5f){
        int bu = (NB - 1) - t;            /* t = descending error position */
        u32 np = 0, nn = 0;
        #pragma unroll
        for (int sh = 0; sh < 4; sh++){
            const u32* base = ph + ((size_t)sh*16 + bk)*2*NB;
            np += base[bu]; nn += base[NB + bu];
        }
        u64 pack = ((u64)np << 32) | nn;
        int lane = t & 63, wid = t >> 6;
        u64 inc = pack;
        #pragma unroll
        for (int off = 1; off < 64; off <<= 1){
            u64 n = __shfl_up(inc, off);
            if (lane >= off) inc += n;
        }
        if (lane == 63) wsum[wid] = inc;
        __syncthreads();
        if (t < 4){
            u64 x = wsum[t];
            #pragma unroll
            for (int off = 1; off < 4; off <<= 1){
                u64 n = __shfl_up(x, off);
                if (t >= off) x += n;
            }
            wsum[t] = x;
        }
        __syncthreads();
        u64 excl = inc - pack + (wid ? wsum[wid - 1] : 0ull);
        float acc = 0.f;
        if (np | nn){
            float Pe = (float)(u32)(excl >> 32), Qe = (float)(u32)excl;
            float Pi = Pe + (float)np, Qi = Qe + (float)nn;
            float je = 1.f - (gts - Pe)/(gts + Qe);
            float ji = 1.f - (gts - Pi)/(gts + Qi);
            u32 bits = ((u32)(bu + BOFF) << 19) | (1u << 18);
            if (bits > 0x40000000u) bits = 0x40000000u;
            acc = __uint_as_float(bits) * (ji - je);
        }
        racc[t] = acc;
        __syncthreads();
        for (int off = 128; off > 0; off >>= 1){
            if (t < off) racc[t] += racc[t + off];
            __syncthreads();
        }
        lv = coef * racc[0];
    }
    if (t == 0){
        __hip_atomic_store(&lov[bk], lv, __ATOMIC_RELEASE, __HIP_MEMORY_SCOPE_AGENT);
        u32 ticket = __hip_atomic_fetch_add(counter, 1u, __ATOMIC_ACQ_REL, __HIP_MEMORY_SCOPE_AGENT);
        if (ticket == 15u){
            float tot = 0.f;
            for (int i = 0; i < 16; i++)
                tot += __hip_atomic_load(&lov[i], __ATOMIC_ACQUIRE, __HIP_MEMORY_SCOPE_AGENT);
            for (int b2 = 0; b2 < BN; b2++){
                float objb = fmaxf(s_val[b2*8+0]+s_val[b2*8+1]+s_val[b2*8+2]+s_val[b2*8+3]
                                  +s_val[b2*8+4]+s_val[b2*8+5]+s_val[b2*8+6]+s_val[b2*8+7], 1.f);
                float vp = 0.f;
                for (int kq = 0; kq < 8; kq++) vp += s_val[b2*8+kq]*s_vrk[b2*8+kq];
                float bg = 0.f, fg = 0.f;
                for (int sh = 0; sh < 8; sh++){
                    bg += unfx(bgsh[(size_t)b2*8 + sh]);
                    fg += unfx(bgsh[(size_t)(2+b2)*8 + sh]);
                }
                tot += 10.f*vp/objb + (bg + fg)*(1.f/(float)NV);
            }
            out[0] = tot * 0.5f;
        }
    }
}

extern "C" void kernel_launch(void* const* d_in, const int* in_sizes, int n_in,
                              void* d_out, int out_size, void* d_ws, size_t ws_size,
                              hipStream_t stream){
    const float* pred = (const float*)d_in[0];
    const int*   inst = (const int*)d_in[2];
    const int*   lab  = (const int*)d_in[3];
    const void*  cim  = d_in[4];

    char* ws = (char*)d_ws;
    size_t off = 0;
    size_t zero0 = off;
    u64* ssh = (u64*)(ws + off);       off += (size_t)4*BN*KK*SSLOT*8;  /* stat shards */
    u64* bgsh = (u64*)(ws + off);      off += (size_t)4*8*8;            /* bg/fg shards */
    u32* ph = (u32*)(ws + off);        off += (size_t)4*16*2*NB*4;      /* sharded hist 128 KB */
    int nzero_u64 = (int)((off - zero0)/8);
    float* lov = (float*)(ws + off);   off += 16*4;
    u32* counter = (u32*)(ws + off);   off += 4;
    u32* fpart = (u32*)(ws + off);     off += NFRONT*4;

    k_front<<<dim3(NFRONT), dim3(512), 0, stream>>>((const u32*)cim, fpart, ssh, nzero_u64, counter);
    k_stats<<<dim3(NSL, BN), dim3(1024), 0, stream>>>(pred, inst, cim, fpart, ssh);
    k_hist<<<dim3(NSL, BN), dim3(1024), 0, stream>>>(ssh, pred, inst, lab, ph, bgsh);
    k_lovasz<<<16, 256, 0, stream>>>(ph, ssh, lov, bgsh, counter, (float*)d_out);
}